// Round 9
// baseline (4275.946 us; speedup 1.0000x reference)
//
#include <hip/hip_runtime.h>
#include <hip/hip_bf16.h>

#define T_ 32
#define B_ 16
#define I_ 512
#define H_ 512
#define OFF_ 441
#define NR_ 71           // I_ - OFF_
#define NC_ 2556         // NR_*(NR_+1)/2
#define G4_ (4*NC_)      // 10224
#define NCP_ 2560        // K padded
#define NPR_ 10240       // padded gate-permuted row count
#define NTIL_ 640        // NPR_/16

typedef __attribute__((ext_vector_type(8))) short bf16x8;
typedef __attribute__((ext_vector_type(4))) float f32x4;

__device__ __forceinline__ ushort bfc(float f) {
    __hip_bfloat16 h = __float2bfloat16(f);
    return *(ushort*)&h;
}
__device__ __forceinline__ float b2f(ushort u) {
    return __uint_as_float((uint)u << 16);
}
__device__ __forceinline__ float sigf(float x) { return 1.f / (1.f + expf(-x)); }

__global__ void k_zero(float* __restrict__ p, int n) {
    int i = blockIdx.x * 256 + threadIdx.x;
    if (i < n) p[i] = 0.f;
}

// x fp32 [512][512] -> bf16 same layout
__global__ void k_cvt_x(const float* __restrict__ x, ushort* __restrict__ xb) {
    int i = blockIdx.x * 256 + threadIdx.x;
    float4 v = ((const float4*)x)[i];
    ushort4 o; o.x = bfc(v.x); o.y = bfc(v.y); o.z = bfc(v.z); o.w = bfc(v.w);
    ((ushort4*)xb)[i] = o;
}

// Wih[l] fp32 [G4][512] -> bf16 gate-permuted [NPR][512]; row n' = 4*jc+q <- q*NC+jc
__global__ void k_cvt_w512p(const float* __restrict__ W0, const float* __restrict__ W1,
                            ushort* __restrict__ dst) {
    int l = blockIdx.z;
    const float* src = l ? W1 : W0;
    size_t idx = (size_t)blockIdx.x * 256 + threadIdx.x;
    int np = (int)(idx >> 7), kq = (int)(idx & 127);
    ushort4 o; o.x = 0; o.y = 0; o.z = 0; o.w = 0;
    int jc = np >> 2, q = np & 3;
    if (jc < NC_) {
        float4 v = *(const float4*)(src + ((size_t)q * NC_ + jc) * I_ + kq * 4);
        o.x = bfc(v.x); o.y = bfc(v.y); o.z = bfc(v.z); o.w = bfc(v.w);
    }
    ((ushort4*)(dst + ((size_t)l * NPR_ + np) * I_))[kq] = o;
}

// Whh[l] fp32 [G4][2556] -> bf16 gate-permuted K-padded [NPR][2560]
__global__ void k_cvt_whhp(const float* __restrict__ W0, const float* __restrict__ W1,
                           ushort* __restrict__ dst) {
    int l = blockIdx.z;
    const float* src = l ? W1 : W0;
    size_t idx = (size_t)blockIdx.x * 256 + threadIdx.x;
    int np = (int)(idx / 640), s = (int)(idx - (size_t)np * 640);
    ushort4 o; o.x = 0; o.y = 0; o.z = 0; o.w = 0;
    int jc = np >> 2, q = np & 3;
    if (jc < NC_ && s < 639) {
        float4 v = *(const float4*)(src + ((size_t)q * NC_ + jc) * NC_ + s * 4);
        o.x = bfc(v.x); o.y = bfc(v.y); o.z = bfc(v.z); o.w = bfc(v.w);
    }
    ((ushort4*)(dst + ((size_t)l * NPR_ + np) * NCP_))[s] = o;
}

// MFMA input GEMM -> preT[l][n'][m] bf16, m = t*16+b; permuted bias added
__global__ __launch_bounds__(256) void k_gih_mfma(const ushort* __restrict__ Xbf,
        const ushort* __restrict__ Wp,
        const float* __restrict__ b0, const float* __restrict__ b1,
        ushort* __restrict__ preT) {
    const int l = blockIdx.z;
    const float* bb = l ? b1 : b0;
    const int wid = threadIdx.x >> 6, lane = threadIdx.x & 63;
    const int nt = blockIdx.x * 4 + wid;
    __shared__ ushort lds_a[32 * 64 * 8];
    const int srow = lane & 15, skq = (lane >> 4) * 8;
    const ushort* wp = Wp + ((size_t)l * NPR_ + nt * 16 + srow) * I_ + skq;
    f32x4 acc[32];
    #pragma unroll
    for (int mt = 0; mt < 32; ++mt) acc[mt] = (f32x4){0.f, 0.f, 0.f, 0.f};
    for (int ks = 0; ks < 16; ++ks) {
        #pragma unroll
        for (int i = 0; i < 8; ++i) {
            int mt = wid * 8 + i;
            bf16x8 xv = *(const bf16x8*)(Xbf + (size_t)(mt * 16 + srow) * I_ + ks * 32 + skq);
            *(bf16x8*)(lds_a + (mt * 64 + lane) * 8) = xv;
        }
        bf16x8 b = *(const bf16x8*)(wp + ks * 32);
        __syncthreads();
        #pragma unroll
        for (int mt = 0; mt < 32; ++mt) {
            bf16x8 a = *(const bf16x8*)(lds_a + (mt * 64 + lane) * 8);
            acc[mt] = __builtin_amdgcn_mfma_f32_16x16x32_bf16(a, b, acc[mt], 0, 0, 0);
        }
        __syncthreads();
    }
    const int n = nt * 16 + srow;
    const float bv = (n < G4_) ? bb[(size_t)(n & 3) * NC_ + (n >> 2)] : 0.f;
    const int r0 = (lane >> 4) * 4;
    ushort* po = preT + ((size_t)l * NPR_ + n) * 512;
    #pragma unroll
    for (int mt = 0; mt < 32; ++mt) {
        ushort4 o;
        o.x = bfc(acc[mt][0] + bv); o.y = bfc(acc[mt][1] + bv);
        o.z = bfc(acc[mt][2] + bv); o.w = bfc(acc[mt][3] + bv);
        *(ushort4*)(po + mt * 16 + r0) = o;
    }
}

// Persistent recurrent loop: weights in VGPRs across all 32 steps.
// 256 blocks (1/CU, LDS-limited) x 640 threads (10 waves = 5 n-tiles x 2 k-halves).
// Hand-rolled inline grid barrier (no __ockl call -> no ABI spill of weight regs).
__global__ __launch_bounds__(640) void k_loop(const ushort* __restrict__ Wp,
        const ushort* __restrict__ preT, ushort* __restrict__ hbf,
        float* __restrict__ hbuf,
        const float* __restrict__ scal_ih, const float* __restrict__ scal_hh,
        uint* __restrict__ bar) {
    __shared__ ushort hlds[320 * 16 * 8];       // 80 KB: h as [kgroup][b][8]
    __shared__ float  accl[10 * 16 * 17];       // 10.6 KB
    __shared__ float  cl[20 * 16];              // c-state [unit][b]
    const int blk = blockIdx.x;
    const int l = blk >> 7;
    const int blk_local = blk & 127;
    const int tid = threadIdx.x;
    const int wid = tid >> 6, lane = tid & 63;
    const int ntile = wid >> 1, khalf = wid & 1;
    const int nlocal = lane & 15;
    const size_t HSpp = (size_t)2 * B_ * NCP_;

    // one-time: load this wave's weight tile into 160 VGPRs
    bf16x8 w[40];
    {
        const ushort* wbase = Wp + ((size_t)l * NPR_ + blk_local * 80 + ntile * 16 + nlocal) * NCP_
                              + khalf * 1280 + (lane >> 4) * 8;
        #pragma unroll
        for (int ks = 0; ks < 40; ++ks) w[ks] = *(const bf16x8*)(wbase + ks * 32);
    }
    if (tid < 320) cl[tid] = 0.f;
    __syncthreads();

    for (int t = 0; t < T_; ++t) {
        // stage h (this layer, current ping-pong) into LDS, k-group-major
        const ushort* hin = hbf + (size_t)(t & 1) * HSpp + (size_t)l * B_ * NCP_;
        #pragma unroll
        for (int i = 0; i < 8; ++i) {
            int c = tid + i * 640;
            int g = c >> 4, b = c & 15;
            *(bf16x8*)(hlds + (((g << 4) + b) << 3)) =
                *(const bf16x8*)(hin + (size_t)b * NCP_ + g * 8);
        }
        __syncthreads();
        // MFMA from register-resident weights
        f32x4 acc = {0.f, 0.f, 0.f, 0.f};
        #pragma unroll
        for (int ks = 0; ks < 40; ++ks) {
            bf16x8 a = *(const bf16x8*)(hlds +
                ((((khalf * 160 + (lane >> 4) + ks * 4) << 4) + nlocal) << 3));
            acc = __builtin_amdgcn_mfma_f32_16x16x32_bf16(a, w[ks], acc, 0, 0, 0);
        }
        {
            float* aw = accl + ((ntile * 2 + khalf) * 16 + nlocal) * 17 + (lane >> 4) * 4;
            aw[0] = acc[0]; aw[1] = acc[1]; aw[2] = acc[2]; aw[3] = acc[3];
        }
        __syncthreads();
        // gate pass: 320 threads, one (unit, batch) each
        if (tid < 320) {
            const int u = tid >> 4, b = tid & 15;
            const int nt = u >> 2;
            const int nl0 = (u & 3) * 4;
            const int row0 = blk_local * 80 + u * 4;
            const ushort* pp = preT + ((size_t)l * NPR_ + row0) * 512 + t * 16 + b;
            float g[4];
            #pragma unroll
            for (int q = 0; q < 4; ++q) {
                g[q] = accl[(nt * 2 + 0) * 16 * 17 + (nl0 + q) * 17 + b]
                     + accl[(nt * 2 + 1) * 16 * 17 + (nl0 + q) * 17 + b]
                     + b2f(pp[(size_t)q * 512]);
            }
            const int jc = blk_local * 20 + u;
            float ci = cl[tid];
            float cn = sigf(g[1]) * ci + sigf(g[0]) * tanhf(g[2]);
            float hn = sigf(g[3]) * tanhf(cn);
            cl[tid] = cn;
            ushort* hout = hbf + (size_t)((t & 1) ^ 1) * HSpp + (size_t)l * B_ * NCP_;
            hout[(size_t)b * NCP_ + jc] = bfc(hn);
            if (jc < NC_) {
                float sc = (l ? scal_hh : scal_ih)[jc];
                hbuf[(((size_t)l * T_ + t) * B_ + b) * NC_ + jc] = hn * sc;
            }
        }
        // ---- inline grid barrier (counter monotone within launch; zeroed per launch) ----
        __threadfence();
        __syncthreads();
        if (tid == 0) {
            __hip_atomic_fetch_add(bar, 1u, __ATOMIC_RELEASE, __HIP_MEMORY_SCOPE_AGENT);
            const uint tgt = 256u * (uint)(t + 1);
            while (__hip_atomic_load(bar, __ATOMIC_ACQUIRE, __HIP_MEMORY_SCOPE_AGENT) < tgt)
                __builtin_amdgcn_s_sleep(8);
        }
        __syncthreads();
        __threadfence();
    }
}

// Bt[k][h] = idct_hid[h][k] for k < 71
__global__ void k_bt(const float* __restrict__ Bh, float* __restrict__ Bt) {
    int idx = blockIdx.x * 256 + threadIdx.x;
    if (idx < NR_ * H_) {
        int k = idx / H_, h = idx - k * H_;
        Bt[idx] = Bh[(size_t)h * H_ + k];
    }
}

// yih[t,b,h] = sum_k Bt[k,h] * v[k]; coeffs pre-scaled in hbuf
__global__ __launch_bounds__(256) void k_yih(const float* __restrict__ x,
        const float* __restrict__ Ain, const float* __restrict__ Bt,
        const float* __restrict__ hbuf0, float* __restrict__ yih) {
    __shared__ float xl[I_];
    __shared__ float u[NR_];
    __shared__ float v[NR_];
    int tb = blockIdx.x;
    int tid = threadIdx.x;
    xl[tid] = x[(size_t)tb * I_ + tid];
    xl[tid + 256] = x[(size_t)tb * I_ + tid + 256];
    __syncthreads();
    if (tid < NR_) {
        float a = 0.f;
        for (int jj = 0; jj < I_; ++jj) a += Ain[(size_t)jj * I_ + tid] * xl[jj];
        u[tid] = a;
    }
    __syncthreads();
    if (tid < NR_) {
        int k = tid;
        int start = k * NR_ - (k * (k - 1)) / 2;
        int cnt = NR_ - k;
        const float* cf = hbuf0 + (size_t)tb * NC_;
        float a = 0.f;
        for (int m = 0; m < cnt; ++m) a += cf[start + m] * u[cnt - 1 - m];
        v[k] = a;
    }
    __syncthreads();
    for (int h = tid; h < H_; h += 256) {
        float a = 0.f;
        #pragma unroll
        for (int k = 0; k < NR_; ++k) a += Bt[(size_t)k * H_ + h] * v[k];
        yih[(size_t)tb * H_ + h] = a;
    }
}

// sequential phase-2 (round-5 version, 112 us): Bt in LDS pitch 520, b128-aligned
#define BTP_ 520
__global__ __launch_bounds__(576) void k_seq(const float* __restrict__ yih,
        const float* __restrict__ Bt, const float* __restrict__ cf_all,
        const float* __restrict__ bias, float* __restrict__ out) {
    __shared__ __align__(16) float bt[NR_ * BTP_];   // 147.7 KB
    __shared__ __align__(16) float hl[H_];
    __shared__ float u[NR_ + 1];
    __shared__ __align__(16) float v[NR_ + 1];
    const int b = blockIdx.x, tid = threadIdx.x;
    for (int i = tid; i < NR_ * H_; i += 576)
        bt[(i >> 9) * BTP_ + (i & 511)] = Bt[i];
    for (int i = tid; i < H_; i += 576) hl[i] = 0.f;
    if (tid == 0) { u[NR_] = 0.f; v[NR_] = 0.f; }
    const float bv = (tid < H_) ? bias[tid] : 0.f;
    const int g = tid >> 3, lane = tid & 7;
    int start = 0, cnt = 0;
    if (g < NR_) { start = g * NR_ - (g * (g - 1)) / 2; cnt = NR_ - g; }
    __syncthreads();
    for (int t = 0; t < T_; ++t) {
        float cfv[9];
        if (g < NR_) {
            const float* cf = cf_all + ((size_t)t * B_ + b) * NC_ + start;
            #pragma unroll
            for (int mi = 0; mi < 9; ++mi) {
                int m = mi * 8 + lane;
                cfv[mi] = cf[m < cnt ? m : (cnt - 1)];
            }
        }
        if (g < NR_) {
            const float* bp = bt + g * BTP_ + lane * 4;
            const float* hp = hl + lane * 4;
            float a = 0.f;
            #pragma unroll
            for (int m = 0; m < 16; ++m) {
                float4 bq = *(const float4*)(bp + m * 32);
                float4 hq = *(const float4*)(hp + m * 32);
                a += bq.x * hq.x + bq.y * hq.y + bq.z * hq.z + bq.w * hq.w;
            }
            a += __shfl_xor(a, 1); a += __shfl_xor(a, 2); a += __shfl_xor(a, 4);
            if (lane == 0) u[g] = a;
        }
        __syncthreads();
        if (g < NR_) {
            float a = 0.f;
            #pragma unroll
            for (int mi = 0; mi < 9; ++mi) {
                int m = mi * 8 + lane;
                a += (m < cnt) ? cfv[mi] * u[cnt - 1 - m] : 0.f;
            }
            a += __shfl_xor(a, 1); a += __shfl_xor(a, 2); a += __shfl_xor(a, 4);
            if (lane == 0) v[g] = a;
        }
        __syncthreads();
        float hv = 0.f;
        if (tid < H_) {
            float4 vv[18];
            #pragma unroll
            for (int q = 0; q < 18; ++q) vv[q] = *(const float4*)(v + q * 4);
            float a0 = 0.f, a1 = 0.f;
            #pragma unroll
            for (int k = 0; k < NR_; ++k) {
                float vk = ((const float*)vv)[k];
                ((k & 1) ? a1 : a0) += bt[k * BTP_ + tid] * vk;
            }
            hv = tanhf(yih[((size_t)t * B_ + b) * H_ + tid] + a0 + a1 + bv);
            out[((size_t)t * B_ + b) * H_ + tid] = hv;
        }
        __syncthreads();
        if (tid < H_) hl[tid] = hv;
        __syncthreads();
    }
}

extern "C" void kernel_launch(void* const* d_in, const int* in_sizes, int n_in,
                              void* d_out, int out_size, void* d_ws, size_t ws_size,
                              hipStream_t stream) {
    const float* x        = (const float*)d_in[0];
    const float* wih_ih   = (const float*)d_in[1];
    const float* wih_hh   = (const float*)d_in[2];
    const float* wih_b    = (const float*)d_in[3];
    const float* whh_ih   = (const float*)d_in[4];
    const float* whh_hh   = (const float*)d_in[5];
    const float* whh_b    = (const float*)d_in[6];
    const float* scal_ih  = (const float*)d_in[7];
    const float* scal_hh  = (const float*)d_in[8];
    const float* bias     = (const float*)d_in[9];
    const float* idct_in  = (const float*)d_in[10];
    const float* idct_hid = (const float*)d_in[11];
    float* out = (float*)d_out;

    const size_t WP_B   = (size_t)2 * NPR_ * NCP_ * 2;    // 104,857,600
    const size_t PRET_B = (size_t)2 * NPR_ * 512 * 2;     //  20,971,520
    const size_t HBUF_B = (size_t)2 * T_ * B_ * NC_ * 4;  //  10,469,376
    const size_t HBF_B  = (size_t)2 * 2 * B_ * NCP_ * 2;  //     327,680
    const size_t BAR_B  = 256;
    const size_t YIH_B  = (size_t)T_ * B_ * H_ * 4;
    const size_t BT_B   = (size_t)NR_ * H_ * 4;
    const size_t need = WP_B + PRET_B + HBUF_B + HBF_B + BAR_B + YIH_B + BT_B + 4096;

    char* ws = (char*)d_ws;
    size_t off = 0;
    auto alloc = [&](size_t bytes) -> void* {
        void* p = (void*)(ws + off);
        off += (bytes + 255) & ~(size_t)255;
        return p;
    };

    if (ws_size < need) return;   // never taken (harness ws ~>160MB); no safe fallback

    ushort* Wp   = (ushort*)alloc(WP_B);
    ushort* preT = (ushort*)alloc(PRET_B);
    float*  hbuf = (float*)alloc(HBUF_B);
    ushort* hbf  = (ushort*)alloc(HBF_B);
    uint*   bar  = (uint*)alloc(BAR_B);
    float*  yih  = (float*)alloc(YIH_B);
    float*  Bt   = (float*)alloc(BT_B);
    ushort* Wih_p = Wp;                              // alias: dead before cvt_whhp
    ushort* Xbf   = (ushort*)((char*)Wp + 21000192); // alias within Wp region

    {   // zero hbf (both ping-pong buffers) + barrier counter (contiguous)
        int n = (int)((HBF_B + BAR_B) / 4);
        hipLaunchKernelGGL(k_zero, dim3((n + 255) / 256), dim3(256), 0, stream,
                           (float*)hbf, n);
    }
    hipLaunchKernelGGL(k_cvt_x, dim3(256), dim3(256), 0, stream, x, Xbf);
    hipLaunchKernelGGL(k_cvt_w512p, dim3(NPR_ * 128 / 256, 1, 2), dim3(256), 0, stream,
                       wih_ih, whh_ih, Wih_p);
    hipLaunchKernelGGL(k_gih_mfma, dim3(160, 1, 2), dim3(256), 0, stream,
                       Xbf, Wih_p, wih_b, whh_b, preT);
    hipLaunchKernelGGL(k_cvt_whhp, dim3(NPR_ * 640 / 256, 1, 2), dim3(256), 0, stream,
                       wih_hh, whh_hh, Wp);

    hipLaunchKernelGGL(k_loop, dim3(256), dim3(640), 0, stream,
                       Wp, preT, hbf, hbuf, scal_ih, scal_hh, bar);

    hipLaunchKernelGGL(k_bt, dim3((NR_ * H_ + 255) / 256), dim3(256), 0, stream,
                       idct_hid, Bt);
    hipLaunchKernelGGL(k_yih, dim3(T_ * B_), dim3(256), 0, stream,
                       x, idct_in, Bt, hbuf, yih);
    hipLaunchKernelGGL(k_seq, dim3(B_), dim3(576), 0, stream,
                       yih, Bt, hbuf + (size_t)T_ * B_ * NC_, bias, out);
}

// Round 10
// 1130.244 us; speedup vs baseline: 3.7832x; 3.7832x over previous
//
#include <hip/hip_runtime.h>
#include <hip/hip_bf16.h>

#define T_ 32
#define B_ 16
#define I_ 512
#define H_ 512
#define OFF_ 441
#define NR_ 71           // I_ - OFF_
#define NC_ 2556         // NR_*(NR_+1)/2
#define G4_ (4*NC_)      // 10224
#define NCP_ 2560        // K padded
#define NPR_ 10240       // padded gate-permuted row count
#define NTIL_ 640        // NPR_/16

typedef __attribute__((ext_vector_type(8))) short bf16x8;
typedef __attribute__((ext_vector_type(4))) float f32x4;

__device__ __forceinline__ ushort bfc(float f) {
    __hip_bfloat16 h = __float2bfloat16(f);
    return *(ushort*)&h;
}
__device__ __forceinline__ float b2f(ushort u) {
    return __uint_as_float((uint)u << 16);
}
__device__ __forceinline__ float sigf(float x) { return 1.f / (1.f + expf(-x)); }

// int8x8 (two uints) -> integer-valued bf16x8 (exact for |v|<=127)
__device__ __forceinline__ bf16x8 dq8(uint lo, uint hi) {
    union { bf16x8 v; ushort us[8]; } r;
    #pragma unroll
    for (int i = 0; i < 4; ++i) {
        int b0 = (int)(signed char)(lo >> (8 * i));
        int b1 = (int)(signed char)(hi >> (8 * i));
        r.us[i]     = (ushort)(__float_as_uint((float)b0) >> 16);
        r.us[i + 4] = (ushort)(__float_as_uint((float)b1) >> 16);
    }
    return r.v;
}

__global__ void k_zero(float* __restrict__ p, int n) {
    int i = blockIdx.x * 256 + threadIdx.x;
    if (i < n) p[i] = 0.f;
}

// x fp32 [512][512] -> bf16 same layout
__global__ void k_cvt_x(const float* __restrict__ x, ushort* __restrict__ xb) {
    int i = blockIdx.x * 256 + threadIdx.x;
    float4 v = ((const float4*)x)[i];
    ushort4 o; o.x = bfc(v.x); o.y = bfc(v.y); o.z = bfc(v.z); o.w = bfc(v.w);
    ((ushort4*)xb)[i] = o;
}

// Wih[l] fp32 [G4][512] -> bf16 gate-permuted [NPR][512]; row n' = 4*jc+q <- q*NC+jc
__global__ void k_cvt_w512p(const float* __restrict__ W0, const float* __restrict__ W1,
                            ushort* __restrict__ dst) {
    int l = blockIdx.z;
    const float* src = l ? W1 : W0;
    size_t idx = (size_t)blockIdx.x * 256 + threadIdx.x;
    int np = (int)(idx >> 7), kq = (int)(idx & 127);
    ushort4 o; o.x = 0; o.y = 0; o.z = 0; o.w = 0;
    int jc = np >> 2, q = np & 3;
    if (jc < NC_) {
        float4 v = *(const float4*)(src + ((size_t)q * NC_ + jc) * I_ + kq * 4);
        o.x = bfc(v.x); o.y = bfc(v.y); o.z = bfc(v.z); o.w = bfc(v.w);
    }
    ((ushort4*)(dst + ((size_t)l * NPR_ + np) * I_))[kq] = o;
}

// Whh[l] fp32 [G4][2556] -> int8 gate-permuted K-padded [NPR][2560] + per-row scale.
// One wave per row: pass1 max|w| (regs), wave-reduce, quantize.
__global__ __launch_bounds__(256) void k_cvt_whh_i8(const float* __restrict__ W0,
        const float* __restrict__ W1,
        signed char* __restrict__ dst, float* __restrict__ sW) {
    const int l = blockIdx.z;
    const float* src = l ? W1 : W0;
    const int np = blockIdx.x * 4 + (threadIdx.x >> 6);
    const int lane = threadIdx.x & 63;
    const int jc = np >> 2, q = np & 3;
    float w[40];
    float mx = 0.f;
    if (jc < NC_) {
        const float* row = src + ((size_t)q * NC_ + jc) * NC_;
        #pragma unroll
        for (int i = 0; i < 40; ++i) {
            int k = lane + i * 64;
            w[i] = (k < NC_) ? row[k] : 0.f;
            mx = fmaxf(mx, fabsf(w[i]));
        }
    } else {
        #pragma unroll
        for (int i = 0; i < 40; ++i) w[i] = 0.f;
    }
    #pragma unroll
    for (int d = 1; d < 64; d <<= 1) mx = fmaxf(mx, __shfl_xor(mx, d));
    const float inv = (mx > 0.f) ? 127.f / mx : 0.f;
    signed char* orow = dst + ((size_t)l * NPR_ + np) * NCP_;
    #pragma unroll
    for (int i = 0; i < 40; ++i) {
        int k = lane + i * 64;
        orow[k] = (signed char)(int)rintf(w[i] * inv);
    }
    if (lane == 0) sW[(size_t)l * NPR_ + np] = (mx > 0.f) ? mx / 127.f : 0.f;
}

// MFMA input GEMM -> preT[l][n'][m] bf16, m = t*16+b; permuted bias added
__global__ __launch_bounds__(256) void k_gih_mfma(const ushort* __restrict__ Xbf,
        const ushort* __restrict__ Wp,
        const float* __restrict__ b0, const float* __restrict__ b1,
        ushort* __restrict__ preT) {
    const int l = blockIdx.z;
    const float* bb = l ? b1 : b0;
    const int wid = threadIdx.x >> 6, lane = threadIdx.x & 63;
    const int nt = blockIdx.x * 4 + wid;
    __shared__ ushort lds_a[32 * 64 * 8];
    const int srow = lane & 15, skq = (lane >> 4) * 8;
    const ushort* wp = Wp + ((size_t)l * NPR_ + nt * 16 + srow) * I_ + skq;
    f32x4 acc[32];
    #pragma unroll
    for (int mt = 0; mt < 32; ++mt) acc[mt] = (f32x4){0.f, 0.f, 0.f, 0.f};
    for (int ks = 0; ks < 16; ++ks) {
        #pragma unroll
        for (int i = 0; i < 8; ++i) {
            int mt = wid * 8 + i;
            bf16x8 xv = *(const bf16x8*)(Xbf + (size_t)(mt * 16 + srow) * I_ + ks * 32 + skq);
            *(bf16x8*)(lds_a + (mt * 64 + lane) * 8) = xv;
        }
        bf16x8 b = *(const bf16x8*)(wp + ks * 32);
        __syncthreads();
        #pragma unroll
        for (int mt = 0; mt < 32; ++mt) {
            bf16x8 a = *(const bf16x8*)(lds_a + (mt * 64 + lane) * 8);
            acc[mt] = __builtin_amdgcn_mfma_f32_16x16x32_bf16(a, b, acc[mt], 0, 0, 0);
        }
        __syncthreads();
    }
    const int n = nt * 16 + srow;
    const float bv = (n < G4_) ? bb[(size_t)(n & 3) * NC_ + (n >> 2)] : 0.f;
    const int r0 = (lane >> 4) * 4;
    ushort* po = preT + ((size_t)l * NPR_ + n) * 512;
    #pragma unroll
    for (int mt = 0; mt < 32; ++mt) {
        ushort4 o;
        o.x = bfc(acc[mt][0] + bv); o.y = bfc(acc[mt][1] + bv);
        o.z = bfc(acc[mt][2] + bv); o.w = bfc(acc[mt][3] + bv);
        *(ushort4*)(po + mt * 16 + r0) = o;
    }
}

// Fused recurrent step, int8 weights: 4 waves/block, K split 4x640 across waves,
// in-register dequant to integer-valued bf16, LDS reduce, row-scale applied in gate.
__global__ __launch_bounds__(256, 4) void k_step(const signed char* __restrict__ Wp8,
        const float* __restrict__ sW, const ushort* __restrict__ preT,
        const ushort* __restrict__ hbf_in, ushort* __restrict__ hbf_out,
        float* __restrict__ cst, float* __restrict__ hbuf,
        const float* __restrict__ scal_ih, const float* __restrict__ scal_hh,
        int t) {
    const int l = blockIdx.z;
    const int nt = blockIdx.x;
    const int tid = threadIdx.x;
    const int w = tid >> 6, lane = tid & 63;
    const int col = lane & 15;
    const int kq = (lane >> 4) * 8;
    const int kbase = w * 640;
    const signed char* wp = Wp8 + ((size_t)l * NPR_ + nt * 16 + col) * NCP_ + kbase + kq;
    const ushort* hp = hbf_in + ((size_t)l * B_ + col) * NCP_ + kbase + kq;
    f32x4 acc = {0.f, 0.f, 0.f, 0.f};
    #pragma unroll 4
    for (int ks = 0; ks < 20; ++ks) {
        uint2 wb = *(const uint2*)(wp + ks * 32);
        bf16x8 a = *(const bf16x8*)(hp + ks * 32);
        acc = __builtin_amdgcn_mfma_f32_16x16x32_bf16(a, dq8(wb.x, wb.y), acc, 0, 0, 0);
    }
    __shared__ float gl[4][16][17];
    const int m0 = (lane >> 4) * 4;
    gl[w][col][m0 + 0] = acc[0];
    gl[w][col][m0 + 1] = acc[1];
    gl[w][col][m0 + 2] = acc[2];
    gl[w][col][m0 + 3] = acc[3];
    __syncthreads();
    // gate pass on first wave: thread -> (b = tid&15, jq = tid>>4)
    if (tid < 64) {
        const int b = tid & 15, jq = tid >> 4;
        const int jc = nt * 4 + jq;
        if (jc < NC_) {
            float g[4];
            #pragma unroll
            for (int q = 0; q < 4; ++q) {
                const int row = nt * 16 + jq * 4 + q;
                float s = gl[0][jq * 4 + q][b] + gl[1][jq * 4 + q][b]
                        + gl[2][jq * 4 + q][b] + gl[3][jq * 4 + q][b];
                g[q] = s * sW[(size_t)l * NPR_ + row]
                     + b2f(preT[((size_t)l * NPR_ + row) * 512 + t * 16 + b]);
            }
            float* cp = cst + ((size_t)l * NC_ + jc) * B_ + b;
            float ci = *cp;
            float cn = sigf(g[1]) * ci + sigf(g[0]) * tanhf(g[2]);
            float hn = sigf(g[3]) * tanhf(cn);
            *cp = cn;
            hbf_out[((size_t)l * B_ + b) * NCP_ + jc] = bfc(hn);
            float sc = (l ? scal_hh : scal_ih)[jc];
            hbuf[(((size_t)l * T_ + t) * B_ + b) * NC_ + jc] = hn * sc;
        }
    }
}

// Bt[k][h] = idct_hid[h][k] for k < 71
__global__ void k_bt(const float* __restrict__ Bh, float* __restrict__ Bt) {
    int idx = blockIdx.x * 256 + threadIdx.x;
    if (idx < NR_ * H_) {
        int k = idx / H_, h = idx - k * H_;
        Bt[idx] = Bh[(size_t)h * H_ + k];
    }
}

// yih[t,b,h] = sum_k Bt[k,h] * v[k]; coeffs pre-scaled in hbuf
__global__ __launch_bounds__(256) void k_yih(const float* __restrict__ x,
        const float* __restrict__ Ain, const float* __restrict__ Bt,
        const float* __restrict__ hbuf0, float* __restrict__ yih) {
    __shared__ float xl[I_];
    __shared__ float u[NR_];
    __shared__ float v[NR_];
    int tb = blockIdx.x;
    int tid = threadIdx.x;
    xl[tid] = x[(size_t)tb * I_ + tid];
    xl[tid + 256] = x[(size_t)tb * I_ + tid + 256];
    __syncthreads();
    if (tid < NR_) {
        float a = 0.f;
        for (int jj = 0; jj < I_; ++jj) a += Ain[(size_t)jj * I_ + tid] * xl[jj];
        u[tid] = a;
    }
    __syncthreads();
    if (tid < NR_) {
        int k = tid;
        int start = k * NR_ - (k * (k - 1)) / 2;
        int cnt = NR_ - k;
        const float* cf = hbuf0 + (size_t)tb * NC_;
        float a = 0.f;
        for (int m = 0; m < cnt; ++m) a += cf[start + m] * u[cnt - 1 - m];
        v[k] = a;
    }
    __syncthreads();
    for (int h = tid; h < H_; h += 256) {
        float a = 0.f;
        #pragma unroll
        for (int k = 0; k < NR_; ++k) a += Bt[(size_t)k * H_ + h] * v[k];
        yih[(size_t)tb * H_ + h] = a;
    }
}

// sequential phase-2 (round-5 verified, 112 us): Bt in LDS pitch 520, b128-aligned
#define BTP_ 520
__global__ __launch_bounds__(576) void k_seq(const float* __restrict__ yih,
        const float* __restrict__ Bt, const float* __restrict__ cf_all,
        const float* __restrict__ bias, float* __restrict__ out) {
    __shared__ __align__(16) float bt[NR_ * BTP_];   // 147.7 KB
    __shared__ __align__(16) float hl[H_];
    __shared__ float u[NR_ + 1];
    __shared__ __align__(16) float v[NR_ + 1];
    const int b = blockIdx.x, tid = threadIdx.x;
    for (int i = tid; i < NR_ * H_; i += 576)
        bt[(i >> 9) * BTP_ + (i & 511)] = Bt[i];
    for (int i = tid; i < H_; i += 576) hl[i] = 0.f;
    if (tid == 0) { u[NR_] = 0.f; v[NR_] = 0.f; }
    const float bv = (tid < H_) ? bias[tid] : 0.f;
    const int g = tid >> 3, lane = tid & 7;
    int start = 0, cnt = 0;
    if (g < NR_) { start = g * NR_ - (g * (g - 1)) / 2; cnt = NR_ - g; }
    __syncthreads();
    for (int t = 0; t < T_; ++t) {
        float cfv[9];
        if (g < NR_) {
            const float* cf = cf_all + ((size_t)t * B_ + b) * NC_ + start;
            #pragma unroll
            for (int mi = 0; mi < 9; ++mi) {
                int m = mi * 8 + lane;
                cfv[mi] = cf[m < cnt ? m : (cnt - 1)];
            }
        }
        if (g < NR_) {
            const float* bp = bt + g * BTP_ + lane * 4;
            const float* hp = hl + lane * 4;
            float a = 0.f;
            #pragma unroll
            for (int m = 0; m < 16; ++m) {
                float4 bq = *(const float4*)(bp + m * 32);
                float4 hq = *(const float4*)(hp + m * 32);
                a += bq.x * hq.x + bq.y * hq.y + bq.z * hq.z + bq.w * hq.w;
            }
            a += __shfl_xor(a, 1); a += __shfl_xor(a, 2); a += __shfl_xor(a, 4);
            if (lane == 0) u[g] = a;
        }
        __syncthreads();
        if (g < NR_) {
            float a = 0.f;
            #pragma unroll
            for (int mi = 0; mi < 9; ++mi) {
                int m = mi * 8 + lane;
                a += (m < cnt) ? cfv[mi] * u[cnt - 1 - m] : 0.f;
            }
            a += __shfl_xor(a, 1); a += __shfl_xor(a, 2); a += __shfl_xor(a, 4);
            if (lane == 0) v[g] = a;
        }
        __syncthreads();
        float hv = 0.f;
        if (tid < H_) {
            float4 vv[18];
            #pragma unroll
            for (int q = 0; q < 18; ++q) vv[q] = *(const float4*)(v + q * 4);
            float a0 = 0.f, a1 = 0.f;
            #pragma unroll
            for (int k = 0; k < NR_; ++k) {
                float vk = ((const float*)vv)[k];
                ((k & 1) ? a1 : a0) += bt[k * BTP_ + tid] * vk;
            }
            hv = tanhf(yih[((size_t)t * B_ + b) * H_ + tid] + a0 + a1 + bv);
            out[((size_t)t * B_ + b) * H_ + tid] = hv;
        }
        __syncthreads();
        if (tid < H_) hl[tid] = hv;
        __syncthreads();
    }
}

extern "C" void kernel_launch(void* const* d_in, const int* in_sizes, int n_in,
                              void* d_out, int out_size, void* d_ws, size_t ws_size,
                              hipStream_t stream) {
    const float* x        = (const float*)d_in[0];
    const float* wih_ih   = (const float*)d_in[1];
    const float* wih_hh   = (const float*)d_in[2];
    const float* wih_b    = (const float*)d_in[3];
    const float* whh_ih   = (const float*)d_in[4];
    const float* whh_hh   = (const float*)d_in[5];
    const float* whh_b    = (const float*)d_in[6];
    const float* scal_ih  = (const float*)d_in[7];
    const float* scal_hh  = (const float*)d_in[8];
    const float* bias     = (const float*)d_in[9];
    const float* idct_in  = (const float*)d_in[10];
    const float* idct_hid = (const float*)d_in[11];
    float* out = (float*)d_out;

    const size_t WP8_B  = (size_t)2 * NPR_ * NCP_;        //  52,428,800 (int8)
    const size_t SW_B   = (size_t)2 * NPR_ * 4;           //      81,920
    const size_t PRET_B = (size_t)2 * NPR_ * 512 * 2;     //  20,971,520
    const size_t HBUF_B = (size_t)2 * T_ * B_ * NC_ * 4;  //  10,469,376
    const size_t HBF_B  = (size_t)2 * 2 * B_ * NCP_ * 2;  //     327,680
    const size_t CST_B  = (size_t)2 * NC_ * B_ * 4;       //     327,168
    const size_t YIH_B  = (size_t)T_ * B_ * H_ * 4;
    const size_t BT_B   = (size_t)NR_ * H_ * 4;
    const size_t need = WP8_B + SW_B + PRET_B + HBUF_B + HBF_B + CST_B + YIH_B + BT_B + 4096;

    char* ws = (char*)d_ws;
    size_t off = 0;
    auto alloc = [&](size_t bytes) -> void* {
        void* p = (void*)(ws + off);
        off += (bytes + 255) & ~(size_t)255;
        return p;
    };

    if (ws_size < need) return;   // harness workspace has always been >160MB

    signed char* Wp8 = (signed char*)alloc(WP8_B);
    float*  sW   = (float*)alloc(SW_B);
    ushort* preT = (ushort*)alloc(PRET_B);
    float*  hbuf = (float*)alloc(HBUF_B);
    ushort* hbf  = (ushort*)alloc(HBF_B);
    float*  cst  = (float*)alloc(CST_B);
    float*  yih  = (float*)alloc(YIH_B);
    float*  Bt   = (float*)alloc(BT_B);
    // aliases inside Wp8 region (dead before k_cvt_whh_i8 runs)
    ushort* Wih_p = (ushort*)Wp8;                      // 21.0 MB
    ushort* Xbf   = (ushort*)((char*)Wp8 + 21000192);  // +0.5 MB, < 52.4 MB

    {   // zero hbf (ping-pong) + cst (contiguous allocs)
        int n = (int)((HBF_B + CST_B) / 4);
        hipLaunchKernelGGL(k_zero, dim3((n + 255) / 256), dim3(256), 0, stream,
                           (float*)hbf, n);
    }
    hipLaunchKernelGGL(k_cvt_x, dim3(256), dim3(256), 0, stream, x, Xbf);
    hipLaunchKernelGGL(k_cvt_w512p, dim3(NPR_ * 128 / 256, 1, 2), dim3(256), 0, stream,
                       wih_ih, whh_ih, Wih_p);
    hipLaunchKernelGGL(k_gih_mfma, dim3(160, 1, 2), dim3(256), 0, stream,
                       Xbf, Wih_p, wih_b, whh_b, preT);
    hipLaunchKernelGGL(k_cvt_whh_i8, dim3(NPR_ / 4, 1, 2), dim3(256), 0, stream,
                       wih_hh, whh_hh, Wp8, sW);

    const size_t HS = (size_t)2 * B_ * NCP_;   // ushorts per ping-pong buffer
    for (int t = 0; t < T_; ++t) {
        const ushort* hin  = hbf + (size_t)(t & 1) * HS;
        ushort*       hout = hbf + (size_t)((t & 1) ^ 1) * HS;
        hipLaunchKernelGGL(k_step, dim3(NTIL_, 1, 2), dim3(256), 0, stream,
                           Wp8, sW, preT, hin, hout, cst, hbuf, scal_ih, scal_hh, t);
    }

    hipLaunchKernelGGL(k_bt, dim3((NR_ * H_ + 255) / 256), dim3(256), 0, stream,
                       idct_hid, Bt);
    hipLaunchKernelGGL(k_yih, dim3(T_ * B_), dim3(256), 0, stream,
                       x, idct_in, Bt, hbuf, yih);
    hipLaunchKernelGGL(k_seq, dim3(B_), dim3(576), 0, stream,
                       yih, Bt, hbuf + (size_t)T_ * B_ * NC_, bias, out);
}